// Round 10
// baseline (285.491 us; speedup 1.0000x reference)
//
#include <hip/hip_runtime.h>
#include <float.h>
#include <math.h>

// ---------------------------------------------------------------------------
// GraphGeneratorX: 3-graph GraphConv network, N=100K nodes, E=3.2M edges.
// Round 10: 3-slab deep pipeline (runtime ws-gated). r9's cold prologue
// (place_o+sort_o ~50us un-overlapped) is paired by keeping 3 CSR slabs live:
//   L1 place_o | L2 [sort_o||place_m] | L3 [sort_m||place_c||agg1_o]
//   L4 [sort_c||agg1_m||agg2_o] | L5 [agg1c||agg2_m] | L6 reduce | L7 final
// Generic block-range dispatchers (DS bodies first, gather bodies last).
// Falls back to an improved 2-slab schedule if ws < ~52MB, then to atomics.
// ---------------------------------------------------------------------------

#define BBITS   8
#define BINSZ   256
#define MAXP    512
#define SRCBITS 17
#define SRCMASK ((1 << SRCBITS) - 1)
#define CAP     9216   // per-bin capacity (mean 8184, sigma~90 -> +11 sigma)
#define EPT     8      // edges/thread in place (chunk = 1024*8)
#define EPT2    9      // edges/thread in sort  (1024*9 == CAP)

__device__ __forceinline__ float eluf(float x) {
  return x > 0.0f ? x : (expf(x) - 1.0f);
}

__device__ __forceinline__ void atomicMaxF(float* addr, float val) {
  int* ia = (int*)addr;
  int old = *ia;
  while (__int_as_float(old) < val) {
    int assumed = old;
    old = atomicCAS(ia, assumed, __float_as_int(val));
    if (old == assumed) break;
  }
}

// ---- device bodies ----------------------------------------------------------

__device__ __forceinline__ void place_body(const int* __restrict__ ei, int e, int P,
                                           int* __restrict__ binCnt, int* __restrict__ buf,
                                           int blk) {
  __shared__ int h[MAXP];
  __shared__ int base[MAXP];
  int t = threadIdx.x;
  for (int i = t; i < P; i += 1024) h[i] = 0;
  __syncthreads();
  const int* src = ei;
  const int* dst = ei + e;
  int lo = blk * (1024 * EPT);
  int v[EPT], bb[EPT], r[EPT];
#pragma unroll
  for (int k = 0; k < EPT; k++) {
    int idx = lo + k * 1024 + t;
    bool ok = idx < e;
    int d = ok ? dst[idx] : 0;
    int s = ok ? src[idx] : 0;
    bb[k] = ok ? (d >> BBITS) : -1;
    v[k] = ((d & (BINSZ - 1)) << SRCBITS) | s;
    r[k] = (bb[k] >= 0) ? atomicAdd(&h[bb[k]], 1) : 0;
  }
  __syncthreads();
  for (int i = t; i < P; i += 1024)
    base[i] = h[i] ? atomicAdd(&binCnt[i], h[i]) : 0;
  __syncthreads();
#pragma unroll
  for (int k = 0; k < EPT; k++) {
    if (bb[k] >= 0) {
      int idx = base[bb[k]] + r[k];
      if (idx < CAP) buf[(size_t)bb[k] * CAP + idx] = v[k];
    }
  }
}

__device__ __forceinline__ void sort_body(const int* __restrict__ binCnt,
                                          int* __restrict__ buf,
                                          int* __restrict__ rowBeg, int* __restrict__ rowEnd,
                                          int n, int p) {
  __shared__ int cnt[BINSZ];
  __shared__ int sc[BINSZ];
  int t = threadIdx.x;
  int nEd = min(binCnt[p], CAP);
  int* pk = buf + (size_t)p * CAP;
  if (t < BINSZ) cnt[t] = 0;
  __syncthreads();
  int v[EPT2], r[EPT2];
#pragma unroll
  for (int k = 0; k < EPT2; k++) {
    int i = k * 1024 + t;
    bool ok = i < nEd;
    v[k] = ok ? pk[i] : 0;
    r[k] = ok ? atomicAdd(&cnt[v[k] >> SRCBITS], 1) : -1;
  }
  __syncthreads();
  if (t < BINSZ) sc[t] = cnt[t];
  __syncthreads();
  for (int d = 1; d < BINSZ; d <<= 1) {
    int x = 0;
    if (t < BINSZ && t >= d) x = sc[t - d];
    __syncthreads();
    if (t < BINSZ) sc[t] += x;
    __syncthreads();
  }
  if (t < BINSZ) {
    int node = p * BINSZ + t;
    if (node < n) {
      int beg = p * CAP + sc[t] - cnt[t];
      rowBeg[node] = beg;
      rowEnd[node] = beg + cnt[t];
    }
  }
  __syncthreads();
#pragma unroll
  for (int k = 0; k < EPT2; k++) {
    if (r[k] >= 0) {
      int loc = v[k] >> SRCBITS;
      pk[sc[loc] - cnt[loc] + r[k]] = v[k] & SRCMASK;
    }
  }
}

__device__ __forceinline__ void agg1om_body(const int* __restrict__ rowBeg,
                                            const int* __restrict__ rowEnd,
                                            const int* __restrict__ src,
                                            const float* __restrict__ x,
                                            const float* __restrict__ wr,
                                            const float* __restrict__ b,
                                            const float* __restrict__ wo,
                                            float* __restrict__ xh8, int n, int tid) {
  int i = tid >> 3, j = tid & 7;
  if (i >= n) return;
  int r0 = rowBeg[i], r1 = rowEnd[i];
  float ax = 0.f, ay = 0.f;
  for (int e2 = r0 + j; e2 < r1; e2 += 8) {
    int s = src[e2];
    float2 v = ((const float2*)x)[s];
    ax += v.x;
    ay += v.y;
  }
  ax += __shfl_xor(ax, 1); ax += __shfl_xor(ax, 2); ax += __shfl_xor(ax, 4);
  ay += __shfl_xor(ay, 1); ay += __shfl_xor(ay, 2); ay += __shfl_xor(ay, 4);
  float2 xv = ((const float2*)x)[i];
  float v = eluf(wr[2 * j] * ax + wr[2 * j + 1] * ay + b[j] + wo[2 * j] * xv.x + wo[2 * j + 1] * xv.y);
  xh8[(size_t)i * 8 + j] = v;
}

__device__ __forceinline__ void agg2pool_body(const int* __restrict__ rowBeg,
                                              const int* __restrict__ rowEnd,
                                              const int* __restrict__ src,
                                              const float* __restrict__ x8,
                                              const float* __restrict__ wr,
                                              const float* __restrict__ b,
                                              const float* __restrict__ wo,
                                              float* __restrict__ bmax, int n,
                                              int tid, int aggblk) {
  __shared__ float wmax[16][16];
  int i = tid >> 3, j = tid & 7;
  float a[8] = {0, 0, 0, 0, 0, 0, 0, 0};
  bool valid = (i < n);
  if (valid) {
    int r0 = rowBeg[i], r1 = rowEnd[i];
    for (int e2 = r0 + j; e2 < r1; e2 += 8) {
      int s = src[e2];
      const float4* xp = (const float4*)(x8 + (size_t)s * 8);
      float4 v0 = xp[0], v1 = xp[1];
      a[0] += v0.x; a[1] += v0.y; a[2] += v0.z; a[3] += v0.w;
      a[4] += v1.x; a[5] += v1.y; a[6] += v1.z; a[7] += v1.w;
    }
  }
#pragma unroll
  for (int k = 0; k < 8; k++) {
    a[k] += __shfl_xor(a[k], 1);
    a[k] += __shfl_xor(a[k], 2);
    a[k] += __shfl_xor(a[k], 4);
  }
  float o0, o1;
  if (valid) {
    const float4* xp = (const float4*)(x8 + (size_t)i * 8);
    float4 x0 = xp[0], x1 = xp[1];
    float xx[8] = {x0.x, x0.y, x0.z, x0.w, x1.x, x1.y, x1.z, x1.w};
    int k0 = 2 * j, k1 = 2 * j + 1;
    o0 = b[k0];
    o1 = b[k1];
#pragma unroll
    for (int l = 0; l < 8; l++) {
      o0 += wr[8 * k0 + l] * a[l] + wo[8 * k0 + l] * xx[l];
      o1 += wr[8 * k1 + l] * a[l] + wo[8 * k1 + l] * xx[l];
    }
  } else {
    o0 = o1 = -FLT_MAX;
  }
#pragma unroll
  for (int d = 8; d < 64; d <<= 1) {
    o0 = fmaxf(o0, __shfl_xor(o0, d));
    o1 = fmaxf(o1, __shfl_xor(o1, d));
  }
  int wid = threadIdx.x >> 6, lane = threadIdx.x & 63;
  if (lane < 8) {
    wmax[wid][2 * lane] = o0;
    wmax[wid][2 * lane + 1] = o1;
  }
  __syncthreads();
  if (threadIdx.x < 16) {
    float v = -FLT_MAX;
#pragma unroll
    for (int w = 0; w < 16; w++) v = fmaxf(v, wmax[w][threadIdx.x]);
    bmax[(size_t)aggblk * 16 + threadIdx.x] = v;
  }
}

__device__ __forceinline__ void agg1c_body(const int* __restrict__ rowBeg,
                                           const int* __restrict__ rowEnd,
                                           const int* __restrict__ src,
                                           const float* __restrict__ cin,
                                           const float* __restrict__ wr,
                                           const float* __restrict__ b,
                                           const float* __restrict__ wo,
                                           const float* __restrict__ w4r,
                                           const float* __restrict__ w4s,
                                           float* __restrict__ yrel,
                                           float* __restrict__ yroot, int n, int tid) {
  int i = tid >> 3, j = tid & 7;
  if (i >= n) return;
  int r0 = rowBeg[i], r1 = rowEnd[i];
  float ax = 0.f, ay = 0.f;
  for (int e2 = r0 + j; e2 < r1; e2 += 8) {
    int s = src[e2];
    float2 v = ((const float2*)cin)[s];
    ax += v.x;
    ay += v.y;
  }
  ax += __shfl_xor(ax, 1); ax += __shfl_xor(ax, 2); ax += __shfl_xor(ax, 4);
  ay += __shfl_xor(ay, 1); ay += __shfl_xor(ay, 2); ay += __shfl_xor(ay, 4);
  float2 xv = ((const float2*)cin)[i];
  float yr0 = 0.f, yr1 = 0.f, ys0 = 0.f, ys1 = 0.f;
#pragma unroll
  for (int kk = 0; kk < 2; kk++) {
    int k = 2 * j + kk;
    float v = eluf(wr[2 * k] * ax + wr[2 * k + 1] * ay + b[k] + wo[2 * k] * xv.x + wo[2 * k + 1] * xv.y);
    yr0 += w4r[k] * v;
    yr1 += w4r[48 + k] * v;
    ys0 += w4s[k] * v;
    ys1 += w4s[48 + k] * v;
  }
  yr0 += __shfl_xor(yr0, 1); yr0 += __shfl_xor(yr0, 2); yr0 += __shfl_xor(yr0, 4);
  yr1 += __shfl_xor(yr1, 1); yr1 += __shfl_xor(yr1, 2); yr1 += __shfl_xor(yr1, 4);
  ys0 += __shfl_xor(ys0, 1); ys0 += __shfl_xor(ys0, 2); ys0 += __shfl_xor(ys0, 4);
  ys1 += __shfl_xor(ys1, 1); ys1 += __shfl_xor(ys1, 2); ys1 += __shfl_xor(ys1, 4);
  if (j == 0) ((float2*)yrel)[i] = make_float2(yr0, yr1);
  if (j == 1) ((float2*)yroot)[i] = make_float2(ys0, ys1);
}

// ---- dispatcher kernels ------------------------------------------------------

__global__ __launch_bounds__(1024) void place_k(const int* __restrict__ ei, int e, int P,
                                                int* __restrict__ binCnt, int* __restrict__ buf) {
  place_body(ei, e, P, binCnt, buf, blockIdx.x);
}

// [0,P): sort X ; [P,...): place Y
__global__ __launch_bounds__(1024) void k_sort_place(const int* __restrict__ bcX,
                                                     int* __restrict__ bufX,
                                                     int* __restrict__ rbX, int* __restrict__ reX,
                                                     int n, int P,
                                                     const int* __restrict__ eiY, int e,
                                                     int* __restrict__ bcY, int* __restrict__ bufY) {
  int b = blockIdx.x;
  if (b < P) { sort_body(bcX, bufX, rbX, reX, n, b); return; }
  place_body(eiY, e, P, bcY, bufY, b - P);
}

// [0,nS): sort Y ; [nS,nS+nPl): place Z ; rest: agg1om X
__global__ __launch_bounds__(1024) void k_sort_place_agg1(
    int nS, int nPl,
    const int* __restrict__ bcY, int* __restrict__ bufY,
    int* __restrict__ rbY, int* __restrict__ reY, int n, int P,
    const int* __restrict__ eiZ, int e,
    int* __restrict__ bcZ, int* __restrict__ bufZ,
    const int* __restrict__ rbX, const int* __restrict__ reX,
    const int* __restrict__ srcX, const float* __restrict__ xX,
    const float* __restrict__ w1r, const float* __restrict__ b1,
    const float* __restrict__ w1s, float* __restrict__ xh8X) {
  int b = blockIdx.x;
  if (b < nS) { sort_body(bcY, bufY, rbY, reY, n, b); return; }
  b -= nS;
  if (b < nPl) { place_body(eiZ, e, P, bcZ, bufZ, b); return; }
  b -= nPl;
  agg1om_body(rbX, reX, srcX, xX, w1r, b1, w1s, xh8X, n, b * 1024 + threadIdx.x);
}

// [0,nS): sort Z ; [nS,nS+nA1): agg1om Y ; rest: agg2pool X -> bmaxX
__global__ __launch_bounds__(1024) void k_sort_agg1_agg2(
    int nS, int nA1,
    const int* __restrict__ bcZ, int* __restrict__ bufZ,
    int* __restrict__ rbZ, int* __restrict__ reZ, int n, int P,
    const int* __restrict__ rbY, const int* __restrict__ reY,
    const int* __restrict__ srcY, const float* __restrict__ xY,
    const float* __restrict__ w1r, const float* __restrict__ b1,
    const float* __restrict__ w1s, float* __restrict__ xh8Y,
    const int* __restrict__ rbX, const int* __restrict__ reX,
    const int* __restrict__ srcX, const float* __restrict__ x8X,
    const float* __restrict__ w2r, const float* __restrict__ b2,
    const float* __restrict__ w2s, float* __restrict__ bmaxX) {
  int b = blockIdx.x;
  if (b < nS) { sort_body(bcZ, bufZ, rbZ, reZ, n, b); return; }
  b -= nS;
  if (b < nA1) { agg1om_body(rbY, reY, srcY, xY, w1r, b1, w1s, xh8Y, n, b * 1024 + threadIdx.x); return; }
  b -= nA1;
  agg2pool_body(rbX, reX, srcX, x8X, w2r, b2, w2s, bmaxX, n, b * 1024 + threadIdx.x, b);
}

// [0,nA1c): agg1c (graph c) ; rest: agg2pool Y -> bmaxY
__global__ __launch_bounds__(1024) void k_agg1c_agg2(
    int nA1c,
    const int* __restrict__ rbC, const int* __restrict__ reC,
    const int* __restrict__ srcC, const float* __restrict__ cin,
    const float* __restrict__ w3r, const float* __restrict__ b3,
    const float* __restrict__ w3s,
    const float* __restrict__ w4r, const float* __restrict__ w4s,
    float* __restrict__ yrel, float* __restrict__ yroot, int n,
    const int* __restrict__ rbY, const int* __restrict__ reY,
    const int* __restrict__ srcY, const float* __restrict__ x8Y,
    const float* __restrict__ w2r, const float* __restrict__ b2,
    const float* __restrict__ w2s, float* __restrict__ bmaxY) {
  int b = blockIdx.x;
  if (b < nA1c) {
    agg1c_body(rbC, reC, srcC, cin, w3r, b3, w3s, w4r, w4s, yrel, yroot, n,
               b * 1024 + threadIdx.x);
    return;
  }
  b -= nA1c;
  agg2pool_body(rbY, reY, srcY, x8Y, w2r, b2, w2s, bmaxY, n,
                b * 1024 + threadIdx.x, b);
}

// reduce bmax[2][nb][16] -> feats[32]; one 512-thread block.
__global__ void reduce_feats_k(const float* __restrict__ bmax, float* __restrict__ feats,
                               int nb) {
  __shared__ float red[512];
  int t = threadIdx.x;
  int ch = t & 31, row = t >> 5;
  int g = ch >> 4, k = ch & 15;
  float v = -FLT_MAX;
  for (int blk = row; blk < nb; blk += 16)
    v = fmaxf(v, bmax[((size_t)g * nb + blk) * 16 + k]);
  red[t] = v;
  __syncthreads();
  if (t < 32) {
    float m = red[t];
#pragma unroll
    for (int r = 1; r < 16; r++) m = fmaxf(m, red[t + 32 * r]);
    feats[t] = m;
  }
}

__global__ __launch_bounds__(1024) void aggfinal_k(const int* __restrict__ rowBeg,
                                                   const int* __restrict__ rowEnd,
                                                   const int* __restrict__ src,
                                                   const float* __restrict__ yrel,
                                                   const float* __restrict__ yroot,
                                                   const float* __restrict__ cin,
                                                   const float* __restrict__ feats,
                                                   const float* __restrict__ w4r,
                                                   const float* __restrict__ b4,
                                                   const float* __restrict__ w4s,
                                                   float* __restrict__ out, int n) {
  int tid = blockIdx.x * 1024 + threadIdx.x;
  int i = tid >> 3, j = tid & 7;
  if (i >= n) return;
  int r0 = rowBeg[i], r1 = rowEnd[i];
  float ay0 = 0.f, ay1 = 0.f;
  for (int e2 = r0 + j; e2 < r1; e2 += 8) {
    int s = src[e2];
    float2 v = ((const float2*)yrel)[s];
    ay0 += v.x;
    ay1 += v.y;
  }
  ay0 += __shfl_xor(ay0, 1); ay0 += __shfl_xor(ay0, 2); ay0 += __shfl_xor(ay0, 4);
  ay1 += __shfl_xor(ay1, 1); ay1 += __shfl_xor(ay1, 2); ay1 += __shfl_xor(ay1, 4);
  if (j != 0) return;
  float pr0 = 0.f, pr1 = 0.f, ps0 = 0.f, ps1 = 0.f;
#pragma unroll
  for (int k = 0; k < 32; k++) {
    float pv = feats[k];
    pr0 += w4r[16 + k] * pv;
    pr1 += w4r[64 + k] * pv;
    ps0 += w4s[16 + k] * pv;
    ps1 += w4s[64 + k] * pv;
  }
  float d = (float)(r1 - r0);
  float2 yrt = ((const float2*)yroot)[i];
  float acc0 = b4[0] + ps0 + d * pr0 + ay0 + yrt.x;
  float acc1 = b4[1] + ps1 + d * pr1 + ay1 + yrt.y;
  float2 cv = ((const float2*)cin)[i];
  float o0 = 1.0f / (1.0f + expf(-acc0)) + cv.x;
  float o1 = 1.0f / (1.0f + expf(-acc1)) + cv.y;
  ((float2*)out)[i] = make_float2(o0, o1);
}

// ---- atomic fallback (only if ws tiny) --------------------------------------

__global__ void init_feats_k(float* feats) {
  int t = threadIdx.x;
  if (t < 32) feats[t] = -FLT_MAX;
}

__global__ void scatter2_k(const float* __restrict__ x, const int* __restrict__ ei,
                           float* __restrict__ agg, float* __restrict__ deg, int e) {
  int idx = blockIdx.x * blockDim.x + threadIdx.x;
  if (idx >= e) return;
  int s = ei[idx];
  int d = ei[e + idx];
  float2 v = ((const float2*)x)[s];
  atomicAdd(&agg[2 * d + 0], v.x);
  atomicAdd(&agg[2 * d + 1], v.y);
  if (deg) atomicAdd(&deg[d], 1.0f);
}

__global__ void scatter8_k(const float* __restrict__ x, const int* __restrict__ ei,
                           float* __restrict__ agg, int e) {
  int idx = blockIdx.x * blockDim.x + threadIdx.x;
  if (idx >= e) return;
  int s = ei[idx];
  int d = ei[e + idx];
  const float4* xp = (const float4*)(x + (size_t)s * 8);
  float4 v0 = xp[0], v1 = xp[1];
  float* ap = agg + (size_t)d * 8;
  atomicAdd(ap + 0, v0.x); atomicAdd(ap + 1, v0.y);
  atomicAdd(ap + 2, v0.z); atomicAdd(ap + 3, v0.w);
  atomicAdd(ap + 4, v1.x); atomicAdd(ap + 5, v1.y);
  atomicAdd(ap + 6, v1.z); atomicAdd(ap + 7, v1.w);
}

__global__ void scatter16_k(const float* __restrict__ x, const int* __restrict__ ei,
                            float* __restrict__ agg, int e) {
  int idx = blockIdx.x * blockDim.x + threadIdx.x;
  if (idx >= e) return;
  int s = ei[idx];
  int d = ei[e + idx];
  const float4* xp = (const float4*)(x + (size_t)s * 16);
  float4 v0 = xp[0], v1 = xp[1], v2 = xp[2], v3 = xp[3];
  float* ap = agg + (size_t)d * 16;
  atomicAdd(ap + 0,  v0.x); atomicAdd(ap + 1,  v0.y);
  atomicAdd(ap + 2,  v0.z); atomicAdd(ap + 3,  v0.w);
  atomicAdd(ap + 4,  v1.x); atomicAdd(ap + 5,  v1.y);
  atomicAdd(ap + 6,  v1.z); atomicAdd(ap + 7,  v1.w);
  atomicAdd(ap + 8,  v2.x); atomicAdd(ap + 9,  v2.y);
  atomicAdd(ap + 10, v2.z); atomicAdd(ap + 11, v2.w);
  atomicAdd(ap + 12, v3.x); atomicAdd(ap + 13, v3.y);
  atomicAdd(ap + 14, v3.z); atomicAdd(ap + 15, v3.w);
}

__global__ void node_2to8_elu_k(const float* __restrict__ agg, const float* __restrict__ xin,
                                const float* __restrict__ wr, const float* __restrict__ b,
                                const float* __restrict__ wo, float* __restrict__ xout, int n) {
  int i = blockIdx.x * blockDim.x + threadIdx.x;
  if (i >= n) return;
  float2 a = ((const float2*)agg)[i];
  float2 x = ((const float2*)xin)[i];
  float out[8];
#pragma unroll
  for (int k = 0; k < 8; k++)
    out[k] = eluf(wr[2 * k] * a.x + wr[2 * k + 1] * a.y + b[k] + wo[2 * k] * x.x + wo[2 * k + 1] * x.y);
  float4* op = (float4*)(xout + (size_t)i * 8);
  op[0] = make_float4(out[0], out[1], out[2], out[3]);
  op[1] = make_float4(out[4], out[5], out[6], out[7]);
}

__global__ void node_2to16_elu_k(const float* __restrict__ agg, const float* __restrict__ xin,
                                 const float* __restrict__ wr, const float* __restrict__ b,
                                 const float* __restrict__ wo, float* __restrict__ xout, int n) {
  int i = blockIdx.x * blockDim.x + threadIdx.x;
  if (i >= n) return;
  float2 a = ((const float2*)agg)[i];
  float2 x = ((const float2*)xin)[i];
  float out[16];
#pragma unroll
  for (int k = 0; k < 16; k++)
    out[k] = eluf(wr[2 * k] * a.x + wr[2 * k + 1] * a.y + b[k] + wo[2 * k] * x.x + wo[2 * k + 1] * x.y);
  float4* op = (float4*)(xout + (size_t)i * 16);
  op[0] = make_float4(out[0],  out[1],  out[2],  out[3]);
  op[1] = make_float4(out[4],  out[5],  out[6],  out[7]);
  op[2] = make_float4(out[8],  out[9],  out[10], out[11]);
  op[3] = make_float4(out[12], out[13], out[14], out[15]);
}

__global__ void conv2_pool_atomic_k(const float* __restrict__ agg, const float* __restrict__ x8,
                                    const float* __restrict__ wr, const float* __restrict__ b,
                                    const float* __restrict__ wo, float* __restrict__ feat, int n) {
  int i = blockIdx.x * blockDim.x + threadIdx.x;
  float out[16];
  if (i < n) {
    const float4* ap = (const float4*)(agg + (size_t)i * 8);
    const float4* xp = (const float4*)(x8 + (size_t)i * 8);
    float4 a0 = ap[0], a1 = ap[1];
    float4 x0 = xp[0], x1 = xp[1];
    float a[8] = {a0.x, a0.y, a0.z, a0.w, a1.x, a1.y, a1.z, a1.w};
    float x[8] = {x0.x, x0.y, x0.z, x0.w, x1.x, x1.y, x1.z, x1.w};
#pragma unroll
    for (int k = 0; k < 16; k++) {
      float v = b[k];
#pragma unroll
      for (int j = 0; j < 8; j++) v += wr[8 * k + j] * a[j] + wo[8 * k + j] * x[j];
      out[k] = v;
    }
  } else {
#pragma unroll
    for (int k = 0; k < 16; k++) out[k] = -FLT_MAX;
  }
#pragma unroll
  for (int k = 0; k < 16; k++) {
    float v = out[k];
    for (int off = 32; off >= 1; off >>= 1) v = fmaxf(v, __shfl_xor(v, off));
    if ((threadIdx.x & 63) == 0) atomicMaxF(&feat[k], v);
  }
}

__global__ void final_atomic_k(const float* __restrict__ agg16, const float* __restrict__ x16,
                               const float* __restrict__ deg, const float* __restrict__ cin,
                               const float* __restrict__ feats, const float* __restrict__ w4r,
                               const float* __restrict__ b4, const float* __restrict__ w4s,
                               float* __restrict__ out, int n) {
  int i = blockIdx.x * blockDim.x + threadIdx.x;
  if (i >= n) return;
  float pr0 = 0.f, pr1 = 0.f, ps0 = 0.f, ps1 = 0.f;
#pragma unroll
  for (int k = 0; k < 32; k++) {
    float pv = feats[k];
    pr0 += w4r[16 + k] * pv;
    pr1 += w4r[48 + 16 + k] * pv;
    ps0 += w4s[16 + k] * pv;
    ps1 += w4s[48 + 16 + k] * pv;
  }
  float d = deg[i];
  float acc0 = b4[0] + ps0 + d * pr0;
  float acc1 = b4[1] + ps1 + d * pr1;
  const float* ag = agg16 + (size_t)i * 16;
  const float* xv = x16 + (size_t)i * 16;
#pragma unroll
  for (int k = 0; k < 16; k++) {
    float a = ag[k], x = xv[k];
    acc0 += w4r[k] * a + w4s[k] * x;
    acc1 += w4r[48 + k] * a + w4s[48 + k] * x;
  }
  float2 cv = ((const float2*)cin)[i];
  float o0 = 1.0f / (1.0f + expf(-acc0)) + cv.x;
  float o1 = 1.0f / (1.0f + expf(-acc1)) + cv.y;
  ((float2*)out)[i] = make_float2(o0, o1);
}

// ---------------------------------------------------------------------------

extern "C" void kernel_launch(void* const* d_in, const int* in_sizes, int n_in,
                              void* d_out, int out_size, void* d_ws, size_t ws_size,
                              hipStream_t stream) {
  const float* o   = (const float*)d_in[0];
  const float* m   = (const float*)d_in[1];
  const float* c   = (const float*)d_in[2];
  const int* ei_o  = (const int*)d_in[3];
  const int* ei_m  = (const int*)d_in[4];
  const int* ei_c  = (const int*)d_in[5];
  const float* w1r = (const float*)d_in[6];
  const float* w1s = (const float*)d_in[7];
  const float* b1  = (const float*)d_in[8];
  const float* w2r = (const float*)d_in[9];
  const float* w2s = (const float*)d_in[10];
  const float* b2  = (const float*)d_in[11];
  const float* w3r = (const float*)d_in[12];
  const float* w3s = (const float*)d_in[13];
  const float* b3  = (const float*)d_in[14];
  const float* w4r = (const float*)d_in[15];
  const float* w4s = (const float*)d_in[16];
  const float* b4  = (const float*)d_in[17];

  const int n = in_sizes[0] / 2;   // 100000
  const int e = in_sizes[3] / 2;   // 3200000
  const int P = (n + BINSZ - 1) >> BBITS;

  const int EBP = (e + 1024 * EPT - 1) / (1024 * EPT);  // place blocks (391)
  const int G1  = (8 * n + 1023) / 1024;                // 8-lane agg blocks (782)

  const size_t slab = (size_t)P * CAP * 4;

  // ---- try 3-slab deep-pipeline layout ----
  size_t off3 = 0;
  int* bufA = (int*)d_ws;                            off3 += slab;
  int* bufB = (int*)((char*)d_ws + off3);            off3 += slab;
  int* bufC = (int*)((char*)d_ws + off3);            off3 += slab;
  int* rbA = (int*)((char*)d_ws + off3);             off3 += (size_t)n * 4;
  int* reA = (int*)((char*)d_ws + off3);             off3 += (size_t)n * 4;
  int* rbB = (int*)((char*)d_ws + off3);             off3 += (size_t)n * 4;
  int* reB = (int*)((char*)d_ws + off3);             off3 += (size_t)n * 4;
  int* rbC = (int*)((char*)d_ws + off3);             off3 += (size_t)n * 4;
  int* reC = (int*)((char*)d_ws + off3);             off3 += (size_t)n * 4;
  float* xh8o = (float*)((char*)d_ws + off3);        off3 += (size_t)n * 8 * 4;
  float* xh8m = (float*)((char*)d_ws + off3);        off3 += (size_t)n * 8 * 4;
  float* bmax = (float*)((char*)d_ws + off3);        off3 += (size_t)2 * G1 * 16 * 4;
  int* binCnt3 = (int*)((char*)d_ws + off3);         off3 += (size_t)3 * MAXP * 4;
  float* feats = (float*)((char*)d_ws + off3);       off3 += 32 * 4;

  float* yrel  = xh8o;                   // xh8o dead after agg2_o
  float* yroot = xh8o + (size_t)2 * n;

  bool ok_base = (P <= MAXP) && (n <= (1 << SRCBITS));
  bool deep_ok = ok_base && (off3 <= ws_size);

  if (deep_ok) {
    int* bcO = binCnt3;
    int* bcM = binCnt3 + MAXP;
    int* bcC = binCnt3 + 2 * MAXP;
    hipMemsetAsync(binCnt3, 0, (size_t)3 * MAXP * sizeof(int), stream);

    // L1: place_o
    place_k<<<EBP, 1024, 0, stream>>>(ei_o, e, P, bcO, bufA);
    // L2: [sort_o || place_m]
    k_sort_place<<<P + EBP, 1024, 0, stream>>>(bcO, bufA, rbA, reA, n, P,
                                               ei_m, e, bcM, bufB);
    // L3: [sort_m || place_c || agg1_o]
    k_sort_place_agg1<<<P + EBP + G1, 1024, 0, stream>>>(
        P, EBP,
        bcM, bufB, rbB, reB, n, P,
        ei_c, e, bcC, bufC,
        rbA, reA, bufA, o, w1r, b1, w1s, xh8o);
    // L4: [sort_c || agg1_m || agg2_o]
    k_sort_agg1_agg2<<<P + G1 + G1, 1024, 0, stream>>>(
        P, G1,
        bcC, bufC, rbC, reC, n, P,
        rbB, reB, bufB, m, w1r, b1, w1s, xh8m,
        rbA, reA, bufA, xh8o, w2r, b2, w2s, bmax);
    // L5: [agg1c || agg2_m]
    k_agg1c_agg2<<<G1 + G1, 1024, 0, stream>>>(
        G1,
        rbC, reC, bufC, c, w3r, b3, w3s, w4r, w4s, yrel, yroot, n,
        rbB, reB, bufB, xh8m, w2r, b2, w2s, bmax + (size_t)G1 * 16);
    // L6: reduce
    reduce_feats_k<<<1, 512, 0, stream>>>(bmax, feats, G1);
    // L7: final
    aggfinal_k<<<G1, 1024, 0, stream>>>(rbC, reC, bufC, yrel, yroot, c,
                                        feats, w4r, b4, w4s, (float*)d_out, n);
    return;
  }

  // ---- 2-slab layout (r9-style, improved schedule) ----
  size_t off2 = 0;
  int* bufA2 = (int*)d_ws;                           off2 += slab;
  int* bufB2 = (int*)((char*)d_ws + off2);           off2 += slab;
  int* rbA2 = (int*)((char*)d_ws + off2);            off2 += (size_t)n * 4;
  int* reA2 = (int*)((char*)d_ws + off2);            off2 += (size_t)n * 4;
  int* rbB2 = (int*)((char*)d_ws + off2);            off2 += (size_t)n * 4;
  int* reB2 = (int*)((char*)d_ws + off2);            off2 += (size_t)n * 4;
  float* xh8o2 = (float*)((char*)d_ws + off2);       off2 += (size_t)n * 8 * 4;
  float* xh8m2 = (float*)((char*)d_ws + off2);       off2 += (size_t)n * 8 * 4;
  float* bmax2 = (float*)((char*)d_ws + off2);       off2 += (size_t)2 * G1 * 16 * 4;
  int* binCnt32 = (int*)((char*)d_ws + off2);        off2 += (size_t)3 * MAXP * 4;
  float* feats2 = (float*)((char*)d_ws + off2);      off2 += 32 * 4;
  float* yrel2  = xh8o2;
  float* yroot2 = xh8o2 + (size_t)2 * n;

  bool two_ok = ok_base && (off2 <= ws_size);

  if (two_ok) {
    int* bcO = binCnt32;
    int* bcM = binCnt32 + MAXP;
    int* bcC = binCnt32 + 2 * MAXP;
    hipMemsetAsync(binCnt32, 0, (size_t)3 * MAXP * sizeof(int), stream);

    // L1: place_o
    place_k<<<EBP, 1024, 0, stream>>>(ei_o, e, P, bcO, bufA2);
    // L2: [sort_o || place_m]
    k_sort_place<<<P + EBP, 1024, 0, stream>>>(bcO, bufA2, rbA2, reA2, n, P,
                                               ei_m, e, bcM, bufB2);
    // L3: [sort_m || agg1_o]
    k_sort_place_agg1<<<P + G1, 1024, 0, stream>>>(
        P, 0,
        bcM, bufB2, rbB2, reB2, n, P,
        ei_c, e, bcC, bufA2,                 // dummy place args (0 blocks)
        rbA2, reA2, bufA2, o, w1r, b1, w1s, xh8o2);
    // L4: agg2_o
    k_sort_agg1_agg2<<<G1, 1024, 0, stream>>>(
        0, 0,
        bcC, bufA2, rbA2, reA2, n, P,        // dummy sort args (0 blocks)
        rbB2, reB2, bufB2, m, w1r, b1, w1s, xh8m2,  // dummy agg1 (0 blocks)
        rbA2, reA2, bufA2, xh8o2, w2r, b2, w2s, bmax2);
    // L5: [place_c(bufA) || agg1_m]
    k_sort_place_agg1<<<EBP + G1, 1024, 0, stream>>>(
        0, EBP,
        bcM, bufB2, rbB2, reB2, n, P,        // dummy sort args (0 blocks)
        ei_c, e, bcC, bufA2,
        rbB2, reB2, bufB2, m, w1r, b1, w1s, xh8m2);
    // L6: [sort_c || agg2_m]
    k_sort_agg1_agg2<<<P + G1, 1024, 0, stream>>>(
        P, 0,
        bcC, bufA2, rbA2, reA2, n, P,
        rbB2, reB2, bufB2, m, w1r, b1, w1s, xh8m2,  // dummy agg1 (0 blocks)
        rbB2, reB2, bufB2, xh8m2, w2r, b2, w2s, bmax2 + (size_t)G1 * 16);
    // L7: reduce ; L8: agg1c ; L9: final
    reduce_feats_k<<<1, 512, 0, stream>>>(bmax2, feats2, G1);
    k_agg1c_agg2<<<G1, 1024, 0, stream>>>(
        G1,
        rbA2, reA2, bufA2, c, w3r, b3, w3s, w4r, w4s, yrel2, yroot2, n,
        rbB2, reB2, bufB2, xh8m2, w2r, b2, w2s, bmax2);  // dummy agg2 (0 blocks)
    aggfinal_k<<<G1, 1024, 0, stream>>>(rbA2, reA2, bufA2, yrel2, yroot2, c,
                                        feats2, w4r, b4, w4s, (float*)d_out, n);
    return;
  }

  // ---- atomic fallback ----
  {
    const int BS = 256;
    const int nbn = (n + BS - 1) / BS;
    float* agg_f   = (float*)d_ws;
    float* xh_f    = agg_f + (size_t)n * 16;
    float* deg_f   = xh_f + (size_t)n * 16;
    float* feats_f = deg_f + n;
    const int nb_e = (e + BS - 1) / BS;
    init_feats_k<<<1, 64, 0, stream>>>(feats_f);
    hipMemsetAsync(agg_f, 0, (size_t)n * 2 * sizeof(float), stream);
    scatter2_k<<<nb_e, BS, 0, stream>>>(o, ei_o, agg_f, nullptr, e);
    node_2to8_elu_k<<<nbn, BS, 0, stream>>>(agg_f, o, w1r, b1, w1s, xh_f, n);
    hipMemsetAsync(agg_f, 0, (size_t)n * 8 * sizeof(float), stream);
    scatter8_k<<<nb_e, BS, 0, stream>>>(xh_f, ei_o, agg_f, e);
    conv2_pool_atomic_k<<<nbn, BS, 0, stream>>>(agg_f, xh_f, w2r, b2, w2s, feats_f, n);
    hipMemsetAsync(agg_f, 0, (size_t)n * 2 * sizeof(float), stream);
    scatter2_k<<<nb_e, BS, 0, stream>>>(m, ei_m, agg_f, nullptr, e);
    node_2to8_elu_k<<<nbn, BS, 0, stream>>>(agg_f, m, w1r, b1, w1s, xh_f, n);
    hipMemsetAsync(agg_f, 0, (size_t)n * 8 * sizeof(float), stream);
    scatter8_k<<<nb_e, BS, 0, stream>>>(xh_f, ei_m, agg_f, e);
    conv2_pool_atomic_k<<<nbn, BS, 0, stream>>>(agg_f, xh_f, w2r, b2, w2s, feats_f + 16, n);
    hipMemsetAsync(agg_f, 0, (size_t)n * 2 * sizeof(float), stream);
    hipMemsetAsync(deg_f, 0, (size_t)n * sizeof(float), stream);
    scatter2_k<<<nb_e, BS, 0, stream>>>(c, ei_c, agg_f, deg_f, e);
    node_2to16_elu_k<<<nbn, BS, 0, stream>>>(agg_f, c, w3r, b3, w3s, xh_f, n);
    hipMemsetAsync(agg_f, 0, (size_t)n * 16 * sizeof(float), stream);
    scatter16_k<<<nb_e, BS, 0, stream>>>(xh_f, ei_c, agg_f, e);
    final_atomic_k<<<nbn, BS, 0, stream>>>(agg_f, xh_f, deg_f, c, feats_f, w4r, b4, w4s,
                                           (float*)d_out, n);
  }
}

// Round 11
// 282.886 us; speedup vs baseline: 1.0092x; 1.0092x over previous
//
#include <hip/hip_runtime.h>
#include <float.h>
#include <math.h>

// ---------------------------------------------------------------------------
// GraphGeneratorX: 3-graph GraphConv network, N=100K nodes, E=3.2M edges.
// Round 11: gather-track MLP. r10 showed launches are gather-track-bound
// (two-level dependent loads: src[e] -> x[src], ~400cy serialized per edge).
// Fix: strip-of-4 software pipelining in all agg bodies -- 4 branch-free src
// loads, then 4 independent feature gathers, then masked accumulate.
// Schedule (3-slab deep pipeline) and CSR build unchanged from r10:
//   L1 place_o | L2 [sort_o||place_m] | L3 [sort_m||place_c||agg1_o]
//   L4 [sort_c||agg1_m||agg2_o] | L5 [agg1c||agg2_m] | L6 reduce | L7 final
// ---------------------------------------------------------------------------

#define BBITS   8
#define BINSZ   256
#define MAXP    512
#define SRCBITS 17
#define SRCMASK ((1 << SRCBITS) - 1)
#define CAP     9216   // per-bin capacity (mean 8184, sigma~90 -> +11 sigma)
#define EPT     8      // edges/thread in place (chunk = 1024*8)
#define EPT2    9      // edges/thread in sort  (1024*9 == CAP)

__device__ __forceinline__ float eluf(float x) {
  return x > 0.0f ? x : (expf(x) - 1.0f);
}

__device__ __forceinline__ void atomicMaxF(float* addr, float val) {
  int* ia = (int*)addr;
  int old = *ia;
  while (__int_as_float(old) < val) {
    int assumed = old;
    old = atomicCAS(ia, assumed, __float_as_int(val));
    if (old == assumed) break;
  }
}

// ---- device bodies ----------------------------------------------------------

__device__ __forceinline__ void place_body(const int* __restrict__ ei, int e, int P,
                                           int* __restrict__ binCnt, int* __restrict__ buf,
                                           int blk) {
  __shared__ int h[MAXP];
  __shared__ int base[MAXP];
  int t = threadIdx.x;
  for (int i = t; i < P; i += 1024) h[i] = 0;
  __syncthreads();
  const int* src = ei;
  const int* dst = ei + e;
  int lo = blk * (1024 * EPT);
  int v[EPT], bb[EPT], r[EPT];
#pragma unroll
  for (int k = 0; k < EPT; k++) {
    int idx = lo + k * 1024 + t;
    bool ok = idx < e;
    int d = ok ? dst[idx] : 0;
    int s = ok ? src[idx] : 0;
    bb[k] = ok ? (d >> BBITS) : -1;
    v[k] = ((d & (BINSZ - 1)) << SRCBITS) | s;
    r[k] = (bb[k] >= 0) ? atomicAdd(&h[bb[k]], 1) : 0;
  }
  __syncthreads();
  for (int i = t; i < P; i += 1024)
    base[i] = h[i] ? atomicAdd(&binCnt[i], h[i]) : 0;
  __syncthreads();
#pragma unroll
  for (int k = 0; k < EPT; k++) {
    if (bb[k] >= 0) {
      int idx = base[bb[k]] + r[k];
      if (idx < CAP) buf[(size_t)bb[k] * CAP + idx] = v[k];
    }
  }
}

__device__ __forceinline__ void sort_body(const int* __restrict__ binCnt,
                                          int* __restrict__ buf,
                                          int* __restrict__ rowBeg, int* __restrict__ rowEnd,
                                          int n, int p) {
  __shared__ int cnt[BINSZ];
  __shared__ int sc[BINSZ];
  int t = threadIdx.x;
  int nEd = min(binCnt[p], CAP);
  int* pk = buf + (size_t)p * CAP;
  if (t < BINSZ) cnt[t] = 0;
  __syncthreads();
  int v[EPT2], r[EPT2];
#pragma unroll
  for (int k = 0; k < EPT2; k++) {
    int i = k * 1024 + t;
    bool ok = i < nEd;
    v[k] = ok ? pk[i] : 0;
    r[k] = ok ? atomicAdd(&cnt[v[k] >> SRCBITS], 1) : -1;
  }
  __syncthreads();
  if (t < BINSZ) sc[t] = cnt[t];
  __syncthreads();
  for (int d = 1; d < BINSZ; d <<= 1) {
    int x = 0;
    if (t < BINSZ && t >= d) x = sc[t - d];
    __syncthreads();
    if (t < BINSZ) sc[t] += x;
    __syncthreads();
  }
  if (t < BINSZ) {
    int node = p * BINSZ + t;
    if (node < n) {
      int beg = p * CAP + sc[t] - cnt[t];
      rowBeg[node] = beg;
      rowEnd[node] = beg + cnt[t];
    }
  }
  __syncthreads();
#pragma unroll
  for (int k = 0; k < EPT2; k++) {
    if (r[k] >= 0) {
      int loc = v[k] >> SRCBITS;
      pk[sc[loc] - cnt[loc] + r[k]] = v[k] & SRCMASK;
    }
  }
}

// strip-of-4 c=2 gather: 4 branch-free src loads, 4 independent gathers.
__device__ __forceinline__ void gather2_strip(const int* __restrict__ src,
                                              const float* __restrict__ x,
                                              int r0j, int r1, float& ax, float& ay) {
  int e2 = r0j;
  while (e2 < r1) {
    bool c1 = e2 + 8 < r1, c2 = e2 + 16 < r1, c3 = e2 + 24 < r1;
    int s0 = src[e2];
    int s1 = src[c1 ? e2 + 8 : e2];
    int s2 = src[c2 ? e2 + 16 : e2];
    int s3 = src[c3 ? e2 + 24 : e2];
    float2 v0 = ((const float2*)x)[s0];
    float2 v1 = ((const float2*)x)[s1];
    float2 v2 = ((const float2*)x)[s2];
    float2 v3 = ((const float2*)x)[s3];
    ax += v0.x; ay += v0.y;
    if (c1) { ax += v1.x; ay += v1.y; }
    if (c2) { ax += v2.x; ay += v2.y; }
    if (c3) { ax += v3.x; ay += v3.y; }
    e2 += 32;
  }
}

__device__ __forceinline__ void agg1om_body(const int* __restrict__ rowBeg,
                                            const int* __restrict__ rowEnd,
                                            const int* __restrict__ src,
                                            const float* __restrict__ x,
                                            const float* __restrict__ wr,
                                            const float* __restrict__ b,
                                            const float* __restrict__ wo,
                                            float* __restrict__ xh8, int n, int tid) {
  int i = tid >> 3, j = tid & 7;
  if (i >= n) return;
  int r0 = rowBeg[i], r1 = rowEnd[i];
  float ax = 0.f, ay = 0.f;
  gather2_strip(src, x, r0 + j, r1, ax, ay);
  ax += __shfl_xor(ax, 1); ax += __shfl_xor(ax, 2); ax += __shfl_xor(ax, 4);
  ay += __shfl_xor(ay, 1); ay += __shfl_xor(ay, 2); ay += __shfl_xor(ay, 4);
  float2 xv = ((const float2*)x)[i];
  float v = eluf(wr[2 * j] * ax + wr[2 * j + 1] * ay + b[j] + wo[2 * j] * xv.x + wo[2 * j + 1] * xv.y);
  xh8[(size_t)i * 8 + j] = v;
}

__device__ __forceinline__ void agg2pool_body(const int* __restrict__ rowBeg,
                                              const int* __restrict__ rowEnd,
                                              const int* __restrict__ src,
                                              const float* __restrict__ x8,
                                              const float* __restrict__ wr,
                                              const float* __restrict__ b,
                                              const float* __restrict__ wo,
                                              float* __restrict__ bmax, int n,
                                              int tid, int aggblk) {
  __shared__ float wmax[16][16];
  int i = tid >> 3, j = tid & 7;
  float a[8] = {0, 0, 0, 0, 0, 0, 0, 0};
  bool valid = (i < n);
  if (valid) {
    int r0 = rowBeg[i], r1 = rowEnd[i];
    int e2 = r0 + j;
    while (e2 < r1) {
      bool c1 = e2 + 8 < r1, c2 = e2 + 16 < r1, c3 = e2 + 24 < r1;
      int s0 = src[e2];
      int s1 = src[c1 ? e2 + 8 : e2];
      int s2 = src[c2 ? e2 + 16 : e2];
      int s3 = src[c3 ? e2 + 24 : e2];
      const float4* p0 = (const float4*)(x8 + (size_t)s0 * 8);
      const float4* p1 = (const float4*)(x8 + (size_t)s1 * 8);
      const float4* p2 = (const float4*)(x8 + (size_t)s2 * 8);
      const float4* p3 = (const float4*)(x8 + (size_t)s3 * 8);
      float4 u0 = p0[0], w0 = p0[1];
      float4 u1 = p1[0], w1 = p1[1];
      float4 u2 = p2[0], w2 = p2[1];
      float4 u3 = p3[0], w3 = p3[1];
      a[0] += u0.x; a[1] += u0.y; a[2] += u0.z; a[3] += u0.w;
      a[4] += w0.x; a[5] += w0.y; a[6] += w0.z; a[7] += w0.w;
      if (c1) {
        a[0] += u1.x; a[1] += u1.y; a[2] += u1.z; a[3] += u1.w;
        a[4] += w1.x; a[5] += w1.y; a[6] += w1.z; a[7] += w1.w;
      }
      if (c2) {
        a[0] += u2.x; a[1] += u2.y; a[2] += u2.z; a[3] += u2.w;
        a[4] += w2.x; a[5] += w2.y; a[6] += w2.z; a[7] += w2.w;
      }
      if (c3) {
        a[0] += u3.x; a[1] += u3.y; a[2] += u3.z; a[3] += u3.w;
        a[4] += w3.x; a[5] += w3.y; a[6] += w3.z; a[7] += w3.w;
      }
      e2 += 32;
    }
  }
#pragma unroll
  for (int k = 0; k < 8; k++) {
    a[k] += __shfl_xor(a[k], 1);
    a[k] += __shfl_xor(a[k], 2);
    a[k] += __shfl_xor(a[k], 4);
  }
  float o0, o1;
  if (valid) {
    const float4* xp = (const float4*)(x8 + (size_t)i * 8);
    float4 x0 = xp[0], x1 = xp[1];
    float xx[8] = {x0.x, x0.y, x0.z, x0.w, x1.x, x1.y, x1.z, x1.w};
    int k0 = 2 * j, k1 = 2 * j + 1;
    o0 = b[k0];
    o1 = b[k1];
#pragma unroll
    for (int l = 0; l < 8; l++) {
      o0 += wr[8 * k0 + l] * a[l] + wo[8 * k0 + l] * xx[l];
      o1 += wr[8 * k1 + l] * a[l] + wo[8 * k1 + l] * xx[l];
    }
  } else {
    o0 = o1 = -FLT_MAX;
  }
#pragma unroll
  for (int d = 8; d < 64; d <<= 1) {
    o0 = fmaxf(o0, __shfl_xor(o0, d));
    o1 = fmaxf(o1, __shfl_xor(o1, d));
  }
  int wid = threadIdx.x >> 6, lane = threadIdx.x & 63;
  if (lane < 8) {
    wmax[wid][2 * lane] = o0;
    wmax[wid][2 * lane + 1] = o1;
  }
  __syncthreads();
  if (threadIdx.x < 16) {
    float v = -FLT_MAX;
#pragma unroll
    for (int w = 0; w < 16; w++) v = fmaxf(v, wmax[w][threadIdx.x]);
    bmax[(size_t)aggblk * 16 + threadIdx.x] = v;
  }
}

__device__ __forceinline__ void agg1c_body(const int* __restrict__ rowBeg,
                                           const int* __restrict__ rowEnd,
                                           const int* __restrict__ src,
                                           const float* __restrict__ cin,
                                           const float* __restrict__ wr,
                                           const float* __restrict__ b,
                                           const float* __restrict__ wo,
                                           const float* __restrict__ w4r,
                                           const float* __restrict__ w4s,
                                           float* __restrict__ yrel,
                                           float* __restrict__ yroot, int n, int tid) {
  int i = tid >> 3, j = tid & 7;
  if (i >= n) return;
  int r0 = rowBeg[i], r1 = rowEnd[i];
  float ax = 0.f, ay = 0.f;
  gather2_strip(src, cin, r0 + j, r1, ax, ay);
  ax += __shfl_xor(ax, 1); ax += __shfl_xor(ax, 2); ax += __shfl_xor(ax, 4);
  ay += __shfl_xor(ay, 1); ay += __shfl_xor(ay, 2); ay += __shfl_xor(ay, 4);
  float2 xv = ((const float2*)cin)[i];
  float yr0 = 0.f, yr1 = 0.f, ys0 = 0.f, ys1 = 0.f;
#pragma unroll
  for (int kk = 0; kk < 2; kk++) {
    int k = 2 * j + kk;
    float v = eluf(wr[2 * k] * ax + wr[2 * k + 1] * ay + b[k] + wo[2 * k] * xv.x + wo[2 * k + 1] * xv.y);
    yr0 += w4r[k] * v;
    yr1 += w4r[48 + k] * v;
    ys0 += w4s[k] * v;
    ys1 += w4s[48 + k] * v;
  }
  yr0 += __shfl_xor(yr0, 1); yr0 += __shfl_xor(yr0, 2); yr0 += __shfl_xor(yr0, 4);
  yr1 += __shfl_xor(yr1, 1); yr1 += __shfl_xor(yr1, 2); yr1 += __shfl_xor(yr1, 4);
  ys0 += __shfl_xor(ys0, 1); ys0 += __shfl_xor(ys0, 2); ys0 += __shfl_xor(ys0, 4);
  ys1 += __shfl_xor(ys1, 1); ys1 += __shfl_xor(ys1, 2); ys1 += __shfl_xor(ys1, 4);
  if (j == 0) ((float2*)yrel)[i] = make_float2(yr0, yr1);
  if (j == 1) ((float2*)yroot)[i] = make_float2(ys0, ys1);
}

// ---- dispatcher kernels ------------------------------------------------------

__global__ __launch_bounds__(1024) void place_k(const int* __restrict__ ei, int e, int P,
                                                int* __restrict__ binCnt, int* __restrict__ buf) {
  place_body(ei, e, P, binCnt, buf, blockIdx.x);
}

// [0,P): sort X ; [P,...): place Y
__global__ __launch_bounds__(1024) void k_sort_place(const int* __restrict__ bcX,
                                                     int* __restrict__ bufX,
                                                     int* __restrict__ rbX, int* __restrict__ reX,
                                                     int n, int P,
                                                     const int* __restrict__ eiY, int e,
                                                     int* __restrict__ bcY, int* __restrict__ bufY) {
  int b = blockIdx.x;
  if (b < P) { sort_body(bcX, bufX, rbX, reX, n, b); return; }
  place_body(eiY, e, P, bcY, bufY, b - P);
}

// [0,nS): sort Y ; [nS,nS+nPl): place Z ; rest: agg1om X
__global__ __launch_bounds__(1024) void k_sort_place_agg1(
    int nS, int nPl,
    const int* __restrict__ bcY, int* __restrict__ bufY,
    int* __restrict__ rbY, int* __restrict__ reY, int n, int P,
    const int* __restrict__ eiZ, int e,
    int* __restrict__ bcZ, int* __restrict__ bufZ,
    const int* __restrict__ rbX, const int* __restrict__ reX,
    const int* __restrict__ srcX, const float* __restrict__ xX,
    const float* __restrict__ w1r, const float* __restrict__ b1,
    const float* __restrict__ w1s, float* __restrict__ xh8X) {
  int b = blockIdx.x;
  if (b < nS) { sort_body(bcY, bufY, rbY, reY, n, b); return; }
  b -= nS;
  if (b < nPl) { place_body(eiZ, e, P, bcZ, bufZ, b); return; }
  b -= nPl;
  agg1om_body(rbX, reX, srcX, xX, w1r, b1, w1s, xh8X, n, b * 1024 + threadIdx.x);
}

// [0,nS): sort Z ; [nS,nS+nA1): agg1om Y ; rest: agg2pool X -> bmaxX
__global__ __launch_bounds__(1024) void k_sort_agg1_agg2(
    int nS, int nA1,
    const int* __restrict__ bcZ, int* __restrict__ bufZ,
    int* __restrict__ rbZ, int* __restrict__ reZ, int n, int P,
    const int* __restrict__ rbY, const int* __restrict__ reY,
    const int* __restrict__ srcY, const float* __restrict__ xY,
    const float* __restrict__ w1r, const float* __restrict__ b1,
    const float* __restrict__ w1s, float* __restrict__ xh8Y,
    const int* __restrict__ rbX, const int* __restrict__ reX,
    const int* __restrict__ srcX, const float* __restrict__ x8X,
    const float* __restrict__ w2r, const float* __restrict__ b2,
    const float* __restrict__ w2s, float* __restrict__ bmaxX) {
  int b = blockIdx.x;
  if (b < nS) { sort_body(bcZ, bufZ, rbZ, reZ, n, b); return; }
  b -= nS;
  if (b < nA1) { agg1om_body(rbY, reY, srcY, xY, w1r, b1, w1s, xh8Y, n, b * 1024 + threadIdx.x); return; }
  b -= nA1;
  agg2pool_body(rbX, reX, srcX, x8X, w2r, b2, w2s, bmaxX, n, b * 1024 + threadIdx.x, b);
}

// [0,nA1c): agg1c (graph c) ; rest: agg2pool Y -> bmaxY
__global__ __launch_bounds__(1024) void k_agg1c_agg2(
    int nA1c,
    const int* __restrict__ rbC, const int* __restrict__ reC,
    const int* __restrict__ srcC, const float* __restrict__ cin,
    const float* __restrict__ w3r, const float* __restrict__ b3,
    const float* __restrict__ w3s,
    const float* __restrict__ w4r, const float* __restrict__ w4s,
    float* __restrict__ yrel, float* __restrict__ yroot, int n,
    const int* __restrict__ rbY, const int* __restrict__ reY,
    const int* __restrict__ srcY, const float* __restrict__ x8Y,
    const float* __restrict__ w2r, const float* __restrict__ b2,
    const float* __restrict__ w2s, float* __restrict__ bmaxY) {
  int b = blockIdx.x;
  if (b < nA1c) {
    agg1c_body(rbC, reC, srcC, cin, w3r, b3, w3s, w4r, w4s, yrel, yroot, n,
               b * 1024 + threadIdx.x);
    return;
  }
  b -= nA1c;
  agg2pool_body(rbY, reY, srcY, x8Y, w2r, b2, w2s, bmaxY, n,
                b * 1024 + threadIdx.x, b);
}

// reduce bmax[2][nb][16] -> feats[32]; one 512-thread block.
__global__ void reduce_feats_k(const float* __restrict__ bmax, float* __restrict__ feats,
                               int nb) {
  __shared__ float red[512];
  int t = threadIdx.x;
  int ch = t & 31, row = t >> 5;
  int g = ch >> 4, k = ch & 15;
  float v = -FLT_MAX;
  for (int blk = row; blk < nb; blk += 16)
    v = fmaxf(v, bmax[((size_t)g * nb + blk) * 16 + k]);
  red[t] = v;
  __syncthreads();
  if (t < 32) {
    float m = red[t];
#pragma unroll
    for (int r = 1; r < 16; r++) m = fmaxf(m, red[t + 32 * r]);
    feats[t] = m;
  }
}

__global__ __launch_bounds__(1024) void aggfinal_k(const int* __restrict__ rowBeg,
                                                   const int* __restrict__ rowEnd,
                                                   const int* __restrict__ src,
                                                   const float* __restrict__ yrel,
                                                   const float* __restrict__ yroot,
                                                   const float* __restrict__ cin,
                                                   const float* __restrict__ feats,
                                                   const float* __restrict__ w4r,
                                                   const float* __restrict__ b4,
                                                   const float* __restrict__ w4s,
                                                   float* __restrict__ out, int n) {
  int tid = blockIdx.x * 1024 + threadIdx.x;
  int i = tid >> 3, j = tid & 7;
  if (i >= n) return;
  int r0 = rowBeg[i], r1 = rowEnd[i];
  float ay0 = 0.f, ay1 = 0.f;
  gather2_strip(src, yrel, r0 + j, r1, ay0, ay1);
  ay0 += __shfl_xor(ay0, 1); ay0 += __shfl_xor(ay0, 2); ay0 += __shfl_xor(ay0, 4);
  ay1 += __shfl_xor(ay1, 1); ay1 += __shfl_xor(ay1, 2); ay1 += __shfl_xor(ay1, 4);
  if (j != 0) return;
  float pr0 = 0.f, pr1 = 0.f, ps0 = 0.f, ps1 = 0.f;
#pragma unroll
  for (int k = 0; k < 32; k++) {
    float pv = feats[k];
    pr0 += w4r[16 + k] * pv;
    pr1 += w4r[64 + k] * pv;
    ps0 += w4s[16 + k] * pv;
    ps1 += w4s[64 + k] * pv;
  }
  float d = (float)(r1 - r0);
  float2 yrt = ((const float2*)yroot)[i];
  float acc0 = b4[0] + ps0 + d * pr0 + ay0 + yrt.x;
  float acc1 = b4[1] + ps1 + d * pr1 + ay1 + yrt.y;
  float2 cv = ((const float2*)cin)[i];
  float o0 = 1.0f / (1.0f + expf(-acc0)) + cv.x;
  float o1 = 1.0f / (1.0f + expf(-acc1)) + cv.y;
  ((float2*)out)[i] = make_float2(o0, o1);
}

// ---- atomic fallback (only if ws tiny) --------------------------------------

__global__ void init_feats_k(float* feats) {
  int t = threadIdx.x;
  if (t < 32) feats[t] = -FLT_MAX;
}

__global__ void scatter2_k(const float* __restrict__ x, const int* __restrict__ ei,
                           float* __restrict__ agg, float* __restrict__ deg, int e) {
  int idx = blockIdx.x * blockDim.x + threadIdx.x;
  if (idx >= e) return;
  int s = ei[idx];
  int d = ei[e + idx];
  float2 v = ((const float2*)x)[s];
  atomicAdd(&agg[2 * d + 0], v.x);
  atomicAdd(&agg[2 * d + 1], v.y);
  if (deg) atomicAdd(&deg[d], 1.0f);
}

__global__ void scatter8_k(const float* __restrict__ x, const int* __restrict__ ei,
                           float* __restrict__ agg, int e) {
  int idx = blockIdx.x * blockDim.x + threadIdx.x;
  if (idx >= e) return;
  int s = ei[idx];
  int d = ei[e + idx];
  const float4* xp = (const float4*)(x + (size_t)s * 8);
  float4 v0 = xp[0], v1 = xp[1];
  float* ap = agg + (size_t)d * 8;
  atomicAdd(ap + 0, v0.x); atomicAdd(ap + 1, v0.y);
  atomicAdd(ap + 2, v0.z); atomicAdd(ap + 3, v0.w);
  atomicAdd(ap + 4, v1.x); atomicAdd(ap + 5, v1.y);
  atomicAdd(ap + 6, v1.z); atomicAdd(ap + 7, v1.w);
}

__global__ void scatter16_k(const float* __restrict__ x, const int* __restrict__ ei,
                            float* __restrict__ agg, int e) {
  int idx = blockIdx.x * blockDim.x + threadIdx.x;
  if (idx >= e) return;
  int s = ei[idx];
  int d = ei[e + idx];
  const float4* xp = (const float4*)(x + (size_t)s * 16);
  float4 v0 = xp[0], v1 = xp[1], v2 = xp[2], v3 = xp[3];
  float* ap = agg + (size_t)d * 16;
  atomicAdd(ap + 0,  v0.x); atomicAdd(ap + 1,  v0.y);
  atomicAdd(ap + 2,  v0.z); atomicAdd(ap + 3,  v0.w);
  atomicAdd(ap + 4,  v1.x); atomicAdd(ap + 5,  v1.y);
  atomicAdd(ap + 6,  v1.z); atomicAdd(ap + 7,  v1.w);
  atomicAdd(ap + 8,  v2.x); atomicAdd(ap + 9,  v2.y);
  atomicAdd(ap + 10, v2.z); atomicAdd(ap + 11, v2.w);
  atomicAdd(ap + 12, v3.x); atomicAdd(ap + 13, v3.y);
  atomicAdd(ap + 14, v3.z); atomicAdd(ap + 15, v3.w);
}

__global__ void node_2to8_elu_k(const float* __restrict__ agg, const float* __restrict__ xin,
                                const float* __restrict__ wr, const float* __restrict__ b,
                                const float* __restrict__ wo, float* __restrict__ xout, int n) {
  int i = blockIdx.x * blockDim.x + threadIdx.x;
  if (i >= n) return;
  float2 a = ((const float2*)agg)[i];
  float2 x = ((const float2*)xin)[i];
  float out[8];
#pragma unroll
  for (int k = 0; k < 8; k++)
    out[k] = eluf(wr[2 * k] * a.x + wr[2 * k + 1] * a.y + b[k] + wo[2 * k] * x.x + wo[2 * k + 1] * x.y);
  float4* op = (float4*)(xout + (size_t)i * 8);
  op[0] = make_float4(out[0], out[1], out[2], out[3]);
  op[1] = make_float4(out[4], out[5], out[6], out[7]);
}

__global__ void node_2to16_elu_k(const float* __restrict__ agg, const float* __restrict__ xin,
                                 const float* __restrict__ wr, const float* __restrict__ b,
                                 const float* __restrict__ wo, float* __restrict__ xout, int n) {
  int i = blockIdx.x * blockDim.x + threadIdx.x;
  if (i >= n) return;
  float2 a = ((const float2*)agg)[i];
  float2 x = ((const float2*)xin)[i];
  float out[16];
#pragma unroll
  for (int k = 0; k < 16; k++)
    out[k] = eluf(wr[2 * k] * a.x + wr[2 * k + 1] * a.y + b[k] + wo[2 * k] * x.x + wo[2 * k + 1] * x.y);
  float4* op = (float4*)(xout + (size_t)i * 16);
  op[0] = make_float4(out[0],  out[1],  out[2],  out[3]);
  op[1] = make_float4(out[4],  out[5],  out[6],  out[7]);
  op[2] = make_float4(out[8],  out[9],  out[10], out[11]);
  op[3] = make_float4(out[12], out[13], out[14], out[15]);
}

__global__ void conv2_pool_atomic_k(const float* __restrict__ agg, const float* __restrict__ x8,
                                    const float* __restrict__ wr, const float* __restrict__ b,
                                    const float* __restrict__ wo, float* __restrict__ feat, int n) {
  int i = blockIdx.x * blockDim.x + threadIdx.x;
  float out[16];
  if (i < n) {
    const float4* ap = (const float4*)(agg + (size_t)i * 8);
    const float4* xp = (const float4*)(x8 + (size_t)i * 8);
    float4 a0 = ap[0], a1 = ap[1];
    float4 x0 = xp[0], x1 = xp[1];
    float a[8] = {a0.x, a0.y, a0.z, a0.w, a1.x, a1.y, a1.z, a1.w};
    float x[8] = {x0.x, x0.y, x0.z, x0.w, x1.x, x1.y, x1.z, x1.w};
#pragma unroll
    for (int k = 0; k < 16; k++) {
      float v = b[k];
#pragma unroll
      for (int j = 0; j < 8; j++) v += wr[8 * k + j] * a[j] + wo[8 * k + j] * x[j];
      out[k] = v;
    }
  } else {
#pragma unroll
    for (int k = 0; k < 16; k++) out[k] = -FLT_MAX;
  }
#pragma unroll
  for (int k = 0; k < 16; k++) {
    float v = out[k];
    for (int off = 32; off >= 1; off >>= 1) v = fmaxf(v, __shfl_xor(v, off));
    if ((threadIdx.x & 63) == 0) atomicMaxF(&feat[k], v);
  }
}

__global__ void final_atomic_k(const float* __restrict__ agg16, const float* __restrict__ x16,
                               const float* __restrict__ deg, const float* __restrict__ cin,
                               const float* __restrict__ feats, const float* __restrict__ w4r,
                               const float* __restrict__ b4, const float* __restrict__ w4s,
                               float* __restrict__ out, int n) {
  int i = blockIdx.x * blockDim.x + threadIdx.x;
  if (i >= n) return;
  float pr0 = 0.f, pr1 = 0.f, ps0 = 0.f, ps1 = 0.f;
#pragma unroll
  for (int k = 0; k < 32; k++) {
    float pv = feats[k];
    pr0 += w4r[16 + k] * pv;
    pr1 += w4r[48 + 16 + k] * pv;
    ps0 += w4s[16 + k] * pv;
    ps1 += w4s[48 + 16 + k] * pv;
  }
  float d = deg[i];
  float acc0 = b4[0] + ps0 + d * pr0;
  float acc1 = b4[1] + ps1 + d * pr1;
  const float* ag = agg16 + (size_t)i * 16;
  const float* xv = x16 + (size_t)i * 16;
#pragma unroll
  for (int k = 0; k < 16; k++) {
    float a = ag[k], x = xv[k];
    acc0 += w4r[k] * a + w4s[k] * x;
    acc1 += w4r[48 + k] * a + w4s[48 + k] * x;
  }
  float2 cv = ((const float2*)cin)[i];
  float o0 = 1.0f / (1.0f + expf(-acc0)) + cv.x;
  float o1 = 1.0f / (1.0f + expf(-acc1)) + cv.y;
  ((float2*)out)[i] = make_float2(o0, o1);
}

// ---------------------------------------------------------------------------

extern "C" void kernel_launch(void* const* d_in, const int* in_sizes, int n_in,
                              void* d_out, int out_size, void* d_ws, size_t ws_size,
                              hipStream_t stream) {
  const float* o   = (const float*)d_in[0];
  const float* m   = (const float*)d_in[1];
  const float* c   = (const float*)d_in[2];
  const int* ei_o  = (const int*)d_in[3];
  const int* ei_m  = (const int*)d_in[4];
  const int* ei_c  = (const int*)d_in[5];
  const float* w1r = (const float*)d_in[6];
  const float* w1s = (const float*)d_in[7];
  const float* b1  = (const float*)d_in[8];
  const float* w2r = (const float*)d_in[9];
  const float* w2s = (const float*)d_in[10];
  const float* b2  = (const float*)d_in[11];
  const float* w3r = (const float*)d_in[12];
  const float* w3s = (const float*)d_in[13];
  const float* b3  = (const float*)d_in[14];
  const float* w4r = (const float*)d_in[15];
  const float* w4s = (const float*)d_in[16];
  const float* b4  = (const float*)d_in[17];

  const int n = in_sizes[0] / 2;   // 100000
  const int e = in_sizes[3] / 2;   // 3200000
  const int P = (n + BINSZ - 1) >> BBITS;

  const int EBP = (e + 1024 * EPT - 1) / (1024 * EPT);  // place blocks (391)
  const int G1  = (8 * n + 1023) / 1024;                // 8-lane agg blocks (782)

  const size_t slab = (size_t)P * CAP * 4;

  // ---- try 3-slab deep-pipeline layout ----
  size_t off3 = 0;
  int* bufA = (int*)d_ws;                            off3 += slab;
  int* bufB = (int*)((char*)d_ws + off3);            off3 += slab;
  int* bufC = (int*)((char*)d_ws + off3);            off3 += slab;
  int* rbA = (int*)((char*)d_ws + off3);             off3 += (size_t)n * 4;
  int* reA = (int*)((char*)d_ws + off3);             off3 += (size_t)n * 4;
  int* rbB = (int*)((char*)d_ws + off3);             off3 += (size_t)n * 4;
  int* reB = (int*)((char*)d_ws + off3);             off3 += (size_t)n * 4;
  int* rbC = (int*)((char*)d_ws + off3);             off3 += (size_t)n * 4;
  int* reC = (int*)((char*)d_ws + off3);             off3 += (size_t)n * 4;
  float* xh8o = (float*)((char*)d_ws + off3);        off3 += (size_t)n * 8 * 4;
  float* xh8m = (float*)((char*)d_ws + off3);        off3 += (size_t)n * 8 * 4;
  float* bmax = (float*)((char*)d_ws + off3);        off3 += (size_t)2 * G1 * 16 * 4;
  int* binCnt3 = (int*)((char*)d_ws + off3);         off3 += (size_t)3 * MAXP * 4;
  float* feats = (float*)((char*)d_ws + off3);       off3 += 32 * 4;

  float* yrel  = xh8o;                   // xh8o dead after agg2_o
  float* yroot = xh8o + (size_t)2 * n;

  bool ok_base = (P <= MAXP) && (n <= (1 << SRCBITS));
  bool deep_ok = ok_base && (off3 <= ws_size);

  if (deep_ok) {
    int* bcO = binCnt3;
    int* bcM = binCnt3 + MAXP;
    int* bcC = binCnt3 + 2 * MAXP;
    hipMemsetAsync(binCnt3, 0, (size_t)3 * MAXP * sizeof(int), stream);

    // L1: place_o
    place_k<<<EBP, 1024, 0, stream>>>(ei_o, e, P, bcO, bufA);
    // L2: [sort_o || place_m]
    k_sort_place<<<P + EBP, 1024, 0, stream>>>(bcO, bufA, rbA, reA, n, P,
                                               ei_m, e, bcM, bufB);
    // L3: [sort_m || place_c || agg1_o]
    k_sort_place_agg1<<<P + EBP + G1, 1024, 0, stream>>>(
        P, EBP,
        bcM, bufB, rbB, reB, n, P,
        ei_c, e, bcC, bufC,
        rbA, reA, bufA, o, w1r, b1, w1s, xh8o);
    // L4: [sort_c || agg1_m || agg2_o]
    k_sort_agg1_agg2<<<P + G1 + G1, 1024, 0, stream>>>(
        P, G1,
        bcC, bufC, rbC, reC, n, P,
        rbB, reB, bufB, m, w1r, b1, w1s, xh8m,
        rbA, reA, bufA, xh8o, w2r, b2, w2s, bmax);
    // L5: [agg1c || agg2_m]
    k_agg1c_agg2<<<G1 + G1, 1024, 0, stream>>>(
        G1,
        rbC, reC, bufC, c, w3r, b3, w3s, w4r, w4s, yrel, yroot, n,
        rbB, reB, bufB, xh8m, w2r, b2, w2s, bmax + (size_t)G1 * 16);
    // L6: reduce
    reduce_feats_k<<<1, 512, 0, stream>>>(bmax, feats, G1);
    // L7: final
    aggfinal_k<<<G1, 1024, 0, stream>>>(rbC, reC, bufC, yrel, yroot, c,
                                        feats, w4r, b4, w4s, (float*)d_out, n);
    return;
  }

  // ---- 2-slab layout (r9-style schedule) ----
  size_t off2 = 0;
  int* bufA2 = (int*)d_ws;                           off2 += slab;
  int* bufB2 = (int*)((char*)d_ws + off2);           off2 += slab;
  int* rbA2 = (int*)((char*)d_ws + off2);            off2 += (size_t)n * 4;
  int* reA2 = (int*)((char*)d_ws + off2);            off2 += (size_t)n * 4;
  int* rbB2 = (int*)((char*)d_ws + off2);            off2 += (size_t)n * 4;
  int* reB2 = (int*)((char*)d_ws + off2);            off2 += (size_t)n * 4;
  float* xh8o2 = (float*)((char*)d_ws + off2);       off2 += (size_t)n * 8 * 4;
  float* xh8m2 = (float*)((char*)d_ws + off2);       off2 += (size_t)n * 8 * 4;
  float* bmax2 = (float*)((char*)d_ws + off2);       off2 += (size_t)2 * G1 * 16 * 4;
  int* binCnt32 = (int*)((char*)d_ws + off2);        off2 += (size_t)3 * MAXP * 4;
  float* feats2 = (float*)((char*)d_ws + off2);      off2 += 32 * 4;
  float* yrel2  = xh8o2;
  float* yroot2 = xh8o2 + (size_t)2 * n;

  bool two_ok = ok_base && (off2 <= ws_size);

  if (two_ok) {
    int* bcO = binCnt32;
    int* bcM = binCnt32 + MAXP;
    int* bcC = binCnt32 + 2 * MAXP;
    hipMemsetAsync(binCnt32, 0, (size_t)3 * MAXP * sizeof(int), stream);

    place_k<<<EBP, 1024, 0, stream>>>(ei_o, e, P, bcO, bufA2);
    k_sort_place<<<P + EBP, 1024, 0, stream>>>(bcO, bufA2, rbA2, reA2, n, P,
                                               ei_m, e, bcM, bufB2);
    k_sort_place_agg1<<<P + G1, 1024, 0, stream>>>(
        P, 0,
        bcM, bufB2, rbB2, reB2, n, P,
        ei_c, e, bcC, bufA2,
        rbA2, reA2, bufA2, o, w1r, b1, w1s, xh8o2);
    k_sort_agg1_agg2<<<G1, 1024, 0, stream>>>(
        0, 0,
        bcC, bufA2, rbA2, reA2, n, P,
        rbB2, reB2, bufB2, m, w1r, b1, w1s, xh8m2,
        rbA2, reA2, bufA2, xh8o2, w2r, b2, w2s, bmax2);
    k_sort_place_agg1<<<EBP + G1, 1024, 0, stream>>>(
        0, EBP,
        bcM, bufB2, rbB2, reB2, n, P,
        ei_c, e, bcC, bufA2,
        rbB2, reB2, bufB2, m, w1r, b1, w1s, xh8m2);
    k_sort_agg1_agg2<<<P + G1, 1024, 0, stream>>>(
        P, 0,
        bcC, bufA2, rbA2, reA2, n, P,
        rbB2, reB2, bufB2, m, w1r, b1, w1s, xh8m2,
        rbB2, reB2, bufB2, xh8m2, w2r, b2, w2s, bmax2 + (size_t)G1 * 16);
    reduce_feats_k<<<1, 512, 0, stream>>>(bmax2, feats2, G1);
    k_agg1c_agg2<<<G1, 1024, 0, stream>>>(
        G1,
        rbA2, reA2, bufA2, c, w3r, b3, w3s, w4r, w4s, yrel2, yroot2, n,
        rbB2, reB2, bufB2, xh8m2, w2r, b2, w2s, bmax2);
    aggfinal_k<<<G1, 1024, 0, stream>>>(rbA2, reA2, bufA2, yrel2, yroot2, c,
                                        feats2, w4r, b4, w4s, (float*)d_out, n);
    return;
  }

  // ---- atomic fallback ----
  {
    const int BS = 256;
    const int nbn = (n + BS - 1) / BS;
    float* agg_f   = (float*)d_ws;
    float* xh_f    = agg_f + (size_t)n * 16;
    float* deg_f   = xh_f + (size_t)n * 16;
    float* feats_f = deg_f + n;
    const int nb_e = (e + BS - 1) / BS;
    init_feats_k<<<1, 64, 0, stream>>>(feats_f);
    hipMemsetAsync(agg_f, 0, (size_t)n * 2 * sizeof(float), stream);
    scatter2_k<<<nb_e, BS, 0, stream>>>(o, ei_o, agg_f, nullptr, e);
    node_2to8_elu_k<<<nbn, BS, 0, stream>>>(agg_f, o, w1r, b1, w1s, xh_f, n);
    hipMemsetAsync(agg_f, 0, (size_t)n * 8 * sizeof(float), stream);
    scatter8_k<<<nb_e, BS, 0, stream>>>(xh_f, ei_o, agg_f, e);
    conv2_pool_atomic_k<<<nbn, BS, 0, stream>>>(agg_f, xh_f, w2r, b2, w2s, feats_f, n);
    hipMemsetAsync(agg_f, 0, (size_t)n * 2 * sizeof(float), stream);
    scatter2_k<<<nb_e, BS, 0, stream>>>(m, ei_m, agg_f, nullptr, e);
    node_2to8_elu_k<<<nbn, BS, 0, stream>>>(agg_f, m, w1r, b1, w1s, xh_f, n);
    hipMemsetAsync(agg_f, 0, (size_t)n * 8 * sizeof(float), stream);
    scatter8_k<<<nb_e, BS, 0, stream>>>(xh_f, ei_m, agg_f, e);
    conv2_pool_atomic_k<<<nbn, BS, 0, stream>>>(agg_f, xh_f, w2r, b2, w2s, feats_f + 16, n);
    hipMemsetAsync(agg_f, 0, (size_t)n * 2 * sizeof(float), stream);
    hipMemsetAsync(deg_f, 0, (size_t)n * sizeof(float), stream);
    scatter2_k<<<nb_e, BS, 0, stream>>>(c, ei_c, agg_f, deg_f, e);
    node_2to16_elu_k<<<nbn, BS, 0, stream>>>(agg_f, c, w3r, b3, w3s, xh_f, n);
    hipMemsetAsync(agg_f, 0, (size_t)n * 16 * sizeof(float), stream);
    scatter16_k<<<nb_e, BS, 0, stream>>>(xh_f, ei_c, agg_f, e);
    final_atomic_k<<<nbn, BS, 0, stream>>>(agg_f, xh_f, deg_f, c, feats_f, w4r, b4, w4s,
                                           (float*)d_out, n);
  }
}